// Round 5
// baseline (162.727 us; speedup 1.0000x reference)
//
#include <hip/hip_runtime.h>
#include <hip/hip_fp16.h>

#define B_SZ 64
#define TAPE_N 262144
#define OUT_N 65536
#define FANIN 16
#define XCDS 8

typedef _Float16 h16v __attribute__((ext_vector_type(16)));  // 32 B
typedef _Float16 h8v  __attribute__((ext_vector_type(8)));   // 16 B
typedef float    f4v  __attribute__((ext_vector_type(4)));   // 16 B clang vec

// ===========================================================================
// Kernel 1 (proven round-4: transpose ONLY, ~16.5 us, at its 100 MB floor).
// Reads all of tape once, writes tape_T [TAPE][64] halfs (row = 128 B).
// LDS conflict audit: both phases exactly 2-way (free on CDNA4, m136).
// ===========================================================================
__global__ __launch_bounds__(256) void transpose_kernel(
    const float* __restrict__ tape, _Float16* __restrict__ tape_T)
{
    __shared__ float lds[64][65];      // [t_local][b]
    const int t0  = blockIdx.x * 64;
    const int tid = threadIdx.x;

    // Read phase: wave reads 4 rows x 256 B contiguous per instruction.
    const int t4 = tid & 15;           // which float4 within the 64-col chunk
    const int b0 = tid >> 4;           // 0..15
    #pragma unroll
    for (int r = 0; r < 4; ++r) {
        const int b = b0 + r * 16;     // 0..63
        const f4v v = __builtin_nontemporal_load(
            (const f4v*)(tape + (size_t)b * TAPE_N + t0 + t4 * 4));
        lds[t4 * 4 + 0][b] = v.x;
        lds[t4 * 4 + 1][b] = v.y;
        lds[t4 * 4 + 2][b] = v.z;
        lds[t4 * 4 + 3][b] = v.w;
    }
    __syncthreads();

    // Write phase: row t of tape_T = 64 halfs = 128 B = 8 chunks of 16 B.
    const int c    = tid & 7;          // 16 B chunk within row
    const int trow = tid >> 3;         // 0..31
    #pragma unroll
    for (int p = 0; p < 2; ++p) {
        const int t = trow + p * 32;
        h8v v;
        #pragma unroll
        for (int j = 0; j < 8; ++j) v[j] = (_Float16)lds[t][c * 8 + j];
        *(h8v*)(tape_T + (size_t)(t0 + t) * 64 + c * 8) = v;   // cached store
    }
}

// ===========================================================================
// Kernel 2 (round-9): TEMPORAL fuse, one uniform block role.
// Phase A (copy prologue): each block streams its 48 KB slice of
//   tape[:, OUT_N:] -> out (12x NT float4 ld+st per thread). Registers are
//   transient (dead before phase B) so regalloc is NOT coupled to the
//   gather (round-4's spatial role-split gave VGPR=80 -> serialized gather).
//   The copy's HBM time hides under other waves' gather-latency shadow.
// Phase B (gather): round-3 proven structure VERBATIM. Quartet-major lanes
//   (o = bid*64 + tid>>2, bq = tid&3 -> each gather instr = 16 coalesced
//   128 B lines), FULL 16-deep static unroll (rule #20: compile-time idx ->
//   registers), no VGPR cap (round-2 lesson), LDS-tiled coalesced epilogue
//   (round-3: removes the 3x partial-line write amplification).
// ===========================================================================
__global__ __launch_bounds__(256) void neuron_copy_kernel(
    const float* __restrict__ tape,
    const _Float16* __restrict__ tape_T,
    const float* __restrict__ weights,
    const float* __restrict__ bias,
    const int*   __restrict__ input_indices,
    const int*   __restrict__ output_indices,
    const int*   __restrict__ act_ids,
    float* __restrict__ out)
{
    __shared__ float so[64][65];       // [b][o_local], +1 pad
    __shared__ int   s_ok;

    const int bid = blockIdx.x;        // 0..1023
    const int tid = threadIdx.x;

    // ---- Phase A: copy this block's slice of tape[:, OUT_N:] -> out ----
    // Slice: batch row b = bid>>4, segment seg = bid&15 of 12288 floats.
    // 12 x (256 thread * 16 B) = 49152 B per block; 1024 blocks = 50.3 MB.
    {
        const int b   = bid >> 4;
        const int seg = bid & 15;
        const f4v* src = (const f4v*)(tape + (size_t)b * TAPE_N + OUT_N
                                      + seg * 12288);
        f4v*       dst = (f4v*)(out + (size_t)b * TAPE_N + OUT_N
                                + seg * 12288);
        f4v v[12];
        #pragma unroll
        for (int s = 0; s < 12; ++s)
            v[s] = __builtin_nontemporal_load(src + tid + s * 256);
        #pragma unroll
        for (int s = 0; s < 12; ++s)
            __builtin_nontemporal_store(v[s], dst + tid + s * 256);
    }

    // ---- Phase B: gather (round-3 verbatim) ----
    const int ol  = tid >> 2;                       // 0..63, output within blk
    const int o   = bid * 64 + ol;
    const int bq  = tid & 3;                        // quartet lane: b = bq*16+k

    if (tid == 0) s_ok = 1;

    const int4*   ip = (const int4*)(input_indices + (size_t)o * FANIN);
    const float4* wp = (const float4*)(weights      + (size_t)o * FANIN);
    const int4   I0 = ip[0], I1 = ip[1], I2 = ip[2], I3 = ip[3];
    const float4 W0 = wp[0], W1 = wp[1], W2 = wp[2], W3 = wp[3];
    const float bs  = bias[o];
    const int   act = act_ids[o];
    const int   od  = output_indices[o];

    const int   idx[16] = {I0.x, I0.y, I0.z, I0.w, I1.x, I1.y, I1.z, I1.w,
                           I2.x, I2.y, I2.z, I2.w, I3.x, I3.y, I3.z, I3.w};
    const float wv[16]  = {W0.x, W0.y, W0.z, W0.w, W1.x, W1.y, W1.z, W1.w,
                           W2.x, W2.y, W2.z, W2.w, W3.x, W3.y, W3.z, W3.w};

    float acc[16];
    #pragma unroll
    for (int k = 0; k < 16; ++k) acc[k] = bs;

    const _Float16* tb = tape_T + bq * 16;          // this quarter's 32 B slot

    #pragma unroll
    for (int f = 0; f < FANIN; ++f) {               // FULL unroll: static idx,
        const h16v v = *(const h16v*)(tb + (size_t)idx[f] * 64);  // 16 in flight
        const float w = wv[f];
        #pragma unroll
        for (int k = 0; k < 16; ++k) acc[k] += w * (float)v[k];
    }

    if (od != o) s_ok = 0;   // benign race: only 0 is ever written

    // Activation -> LDS tile.
    #pragma unroll
    for (int k = 0; k < 16; ++k) {
        const float x = acc[k];
        float z = (act == 1) ? 0.5f * x : x;
        z = fminf(fmaxf(z, -15.0f), 15.0f);
        const float e  = __expf(-2.0f * z);
        const float th = (1.0f - e) / (1.0f + e);   // tanh(z)
        const float y = (act == 0) ? fmaxf(x, 0.0f)
                       : (act == 1) ? 0.5f * (th + 1.0f)
                                    : th;
        so[bq * 16 + k][ol] = y;
    }
    __syncthreads();

    if (s_ok) {
        // Coalesced tile write: 4 rows x 256 B contiguous per wave-instr,
        // full-line NT stores (no partial-line churn).
        const int c4 = tid & 15;
        const int rb = tid >> 4;       // 0..15
        const int o0 = bid * 64;
        #pragma unroll
        for (int p = 0; p < 4; ++p) {
            const int r = rb + p * 16;
            f4v v;
            v.x = so[r][c4 * 4 + 0];
            v.y = so[r][c4 * 4 + 1];
            v.z = so[r][c4 * 4 + 2];
            v.w = so[r][c4 * 4 + 3];
            __builtin_nontemporal_store(
                v, (f4v*)(out + (size_t)r * TAPE_N + o0 + c4 * 4));
        }
    } else {
        // Fallback: honest scatter via output_indices.
        #pragma unroll
        for (int k = 0; k < 16; ++k)
            __builtin_nontemporal_store(
                so[bq * 16 + k][ol],
                out + (size_t)(bq * 16 + k) * TAPE_N + od);
    }
}

// ===========================================================================
// Fallback path (ws too small): XCD-phased scalar gather on fp32 tape.
// ===========================================================================
__global__ __launch_bounds__(256) void copy_tape_kernel(
    const float4* __restrict__ src, float4* __restrict__ dst, int n4)
{
    int i = blockIdx.x * blockDim.x + threadIdx.x;
    const int stride = gridDim.x * blockDim.x;
    for (; i < n4; i += stride) dst[i] = src[i];
}

__global__ __launch_bounds__(256) void neuron_kernel(
    const float* __restrict__ tape,
    const float* __restrict__ weights,
    const float* __restrict__ bias,
    const int*   __restrict__ input_indices,
    const int*   __restrict__ output_indices,
    const int*   __restrict__ act_ids,
    float* __restrict__ out)
{
    const int grp = blockIdx.x & (XCDS - 1);
    const int j   = blockIdx.x >> 3;
    const int o   = j * 256 + threadIdx.x;

    const int4*   ip = (const int4*)(input_indices + (size_t)o * FANIN);
    const float4* wp = (const float4*)(weights      + (size_t)o * FANIN);
    const int4   i0 = ip[0], i1 = ip[1], i2 = ip[2], i3 = ip[3];
    const float4 w0 = wp[0], w1 = wp[1], w2 = wp[2], w3 = wp[3];
    const float bs  = bias[o];
    const int   act = act_ids[o];
    const int   od  = output_indices[o];

    const int b0 = grp * 8;
    #pragma unroll 1
    for (int r = 0; r < 8; ++r) {
        const int b = b0 + r;
        const float* __restrict__ t = tape + (size_t)b * TAPE_N;
        float g0  = t[i0.x], g1  = t[i0.y], g2  = t[i0.z], g3  = t[i0.w];
        float g4  = t[i1.x], g5  = t[i1.y], g6  = t[i1.z], g7  = t[i1.w];
        float g8  = t[i2.x], g9  = t[i2.y], g10 = t[i2.z], g11 = t[i2.w];
        float g12 = t[i3.x], g13 = t[i3.y], g14 = t[i3.z], g15 = t[i3.w];

        float acc = bs;
        acc += g0*w0.x;  acc += g1*w0.y;  acc += g2*w0.z;  acc += g3*w0.w;
        acc += g4*w1.x;  acc += g5*w1.y;  acc += g6*w1.z;  acc += g7*w1.w;
        acc += g8*w2.x;  acc += g9*w2.y;  acc += g10*w2.z; acc += g11*w2.w;
        acc += g12*w3.x; acc += g13*w3.y; acc += g14*w3.z; acc += g15*w3.w;

        const float x = acc;
        float z = (act == 1) ? 0.5f * x : x;
        z = fminf(fmaxf(z, -15.0f), 15.0f);
        const float e  = __expf(-2.0f * z);
        const float th = (1.0f - e) / (1.0f + e);
        const float y = (act == 0) ? fmaxf(x, 0.0f)
                       : (act == 1) ? 0.5f * (th + 1.0f)
                                    : th;

        out[(size_t)b * TAPE_N + od] = y;
    }
}

extern "C" void kernel_launch(void* const* d_in, const int* in_sizes, int n_in,
                              void* d_out, int out_size, void* d_ws, size_t ws_size,
                              hipStream_t stream)
{
    const float* tape           = (const float*)d_in[0];
    const float* weights        = (const float*)d_in[1];
    const float* bias           = (const float*)d_in[2];
    const int*   input_indices  = (const int*)d_in[3];
    const int*   output_indices = (const int*)d_in[4];
    const int*   act_ids        = (const int*)d_in[5];
    float*       out            = (float*)d_out;

    const size_t need = (size_t)TAPE_N * B_SZ * sizeof(_Float16);  // 32 MiB

    if (ws_size >= need) {
        _Float16* tape_T = (_Float16*)d_ws;
        // Kernel 1: pure fp16 transpose. 262144/64 = 4096 blocks.
        transpose_kernel<<<TAPE_N / 64, 256, 0, stream>>>(tape, tape_T);
        // Kernel 2: 1024 blocks; each copies 48 KB of tape[:,OUT_N:] then
        // gathers 64 outputs (copy HBM time hides under gather latency).
        neuron_copy_kernel<<<OUT_N / 64, 256, 0, stream>>>(
            tape, tape_T, weights, bias, input_indices, output_indices,
            act_ids, out);
    } else {
        const int n4 = (B_SZ * TAPE_N) / 4;
        copy_tape_kernel<<<4096, 256, 0, stream>>>(
            (const float4*)tape, (float4*)out, n4);
        neuron_kernel<<<XCDS * (OUT_N / 256), 256, 0, stream>>>(
            tape, weights, bias, input_indices, output_indices, act_ids, out);
    }
}

// Round 6
// 161.548 us; speedup vs baseline: 1.0073x; 1.0073x over previous
//
#include <hip/hip_runtime.h>
#include <hip/hip_fp16.h>

#define B_SZ 64
#define TAPE_N 262144
#define OUT_N 65536
#define FANIN 16
#define XCDS 8

typedef _Float16 h16v __attribute__((ext_vector_type(16)));  // 32 B
typedef _Float16 h8v  __attribute__((ext_vector_type(8)));   // 16 B
typedef float    f4v  __attribute__((ext_vector_type(4)));   // 16 B clang vec

// ===========================================================================
// Kernel 1 (proven round-4: transpose ONLY, ~16.5 us, at its 100 MB floor:
// 6.1 TB/s achieved). Reads tape once, writes tape_T [TAPE][64] halfs
// (row = 128 B). LDS conflict audit: both phases 2-way (free, m136).
// ===========================================================================
__global__ __launch_bounds__(256) void transpose_kernel(
    const float* __restrict__ tape, _Float16* __restrict__ tape_T)
{
    __shared__ float lds[64][65];      // [t_local][b]
    const int t0  = blockIdx.x * 64;
    const int tid = threadIdx.x;

    // Read phase: wave reads 4 rows x 256 B contiguous per instruction.
    const int t4 = tid & 15;           // which float4 within the 64-col chunk
    const int b0 = tid >> 4;           // 0..15
    #pragma unroll
    for (int r = 0; r < 4; ++r) {
        const int b = b0 + r * 16;     // 0..63
        const f4v v = __builtin_nontemporal_load(
            (const f4v*)(tape + (size_t)b * TAPE_N + t0 + t4 * 4));
        lds[t4 * 4 + 0][b] = v.x;
        lds[t4 * 4 + 1][b] = v.y;
        lds[t4 * 4 + 2][b] = v.z;
        lds[t4 * 4 + 3][b] = v.w;
    }
    __syncthreads();

    // Write phase: row t of tape_T = 64 halfs = 128 B = 8 chunks of 16 B.
    const int c    = tid & 7;          // 16 B chunk within row
    const int trow = tid >> 3;         // 0..31
    #pragma unroll
    for (int p = 0; p < 2; ++p) {
        const int t = trow + p * 32;
        h8v v;
        #pragma unroll
        for (int j = 0; j < 8; ++j) v[j] = (_Float16)lds[t][c * 8 + j];
        *(h8v*)(tape_T + (size_t)(t0 + t) * 64 + c * 8) = v;   // cached store
    }
}

// ---------------------------------------------------------------------------
// Phase functions for the fused kernel (uniform code -> uniform regalloc;
// round-5 showed gather at VGPR=80 runs at full 25.5 us speed).
// ---------------------------------------------------------------------------
__device__ __forceinline__ void copy_phase(
    const float* __restrict__ tape, float* __restrict__ out,
    int bid, int tid)
{
    // Slice: batch row b = bid>>4, segment seg = bid&15 of 12288 floats.
    // 12 x (256 threads * 16 B) = 49152 B per block; 1024 blocks = 50.3 MB.
    const int b   = bid >> 4;
    const int seg = bid & 15;
    const f4v* src = (const f4v*)(tape + (size_t)b * TAPE_N + OUT_N
                                  + seg * 12288);
    f4v*       dst = (f4v*)(out + (size_t)b * TAPE_N + OUT_N + seg * 12288);
    f4v v[12];
    #pragma unroll
    for (int s = 0; s < 12; ++s)
        v[s] = __builtin_nontemporal_load(src + tid + s * 256);
    #pragma unroll
    for (int s = 0; s < 12; ++s)
        __builtin_nontemporal_store(v[s], dst + tid + s * 256);
}

__device__ __forceinline__ void gather_phase(
    const _Float16* __restrict__ tape_T,
    const float* __restrict__ weights,
    const float* __restrict__ bias,
    const int*   __restrict__ input_indices,
    const int*   __restrict__ output_indices,
    const int*   __restrict__ act_ids,
    float* __restrict__ out,
    float (*so)[65], int* s_ok, int bid, int tid)
{
    // Round-3 proven structure VERBATIM. Quartet-major lanes (each gather
    // instr = 16 coalesced 128 B lines), FULL 16-deep static unroll
    // (rule #20), LDS-tiled coalesced epilogue (kills 3x write amp).
    const int ol  = tid >> 2;                       // 0..63, output within blk
    const int o   = bid * 64 + ol;
    const int bq  = tid & 3;                        // quartet lane: b = bq*16+k

    if (tid == 0) *s_ok = 1;

    const int4*   ip = (const int4*)(input_indices + (size_t)o * FANIN);
    const float4* wp = (const float4*)(weights      + (size_t)o * FANIN);
    const int4   I0 = ip[0], I1 = ip[1], I2 = ip[2], I3 = ip[3];
    const float4 W0 = wp[0], W1 = wp[1], W2 = wp[2], W3 = wp[3];
    const float bs  = bias[o];
    const int   act = act_ids[o];
    const int   od  = output_indices[o];

    const int   idx[16] = {I0.x, I0.y, I0.z, I0.w, I1.x, I1.y, I1.z, I1.w,
                           I2.x, I2.y, I2.z, I2.w, I3.x, I3.y, I3.z, I3.w};
    const float wv[16]  = {W0.x, W0.y, W0.z, W0.w, W1.x, W1.y, W1.z, W1.w,
                           W2.x, W2.y, W2.z, W2.w, W3.x, W3.y, W3.z, W3.w};

    float acc[16];
    #pragma unroll
    for (int k = 0; k < 16; ++k) acc[k] = bs;

    const _Float16* tb = tape_T + bq * 16;          // this quarter's 32 B slot

    #pragma unroll
    for (int f = 0; f < FANIN; ++f) {               // FULL unroll: static idx
        const h16v v = *(const h16v*)(tb + (size_t)idx[f] * 64);
        const float w = wv[f];
        #pragma unroll
        for (int k = 0; k < 16; ++k) acc[k] += w * (float)v[k];
    }

    if (od != o) *s_ok = 0;   // benign race: only 0 is ever written

    // Activation -> LDS tile.
    #pragma unroll
    for (int k = 0; k < 16; ++k) {
        const float x = acc[k];
        float z = (act == 1) ? 0.5f * x : x;
        z = fminf(fmaxf(z, -15.0f), 15.0f);
        const float e  = __expf(-2.0f * z);
        const float th = (1.0f - e) / (1.0f + e);   // tanh(z)
        const float y = (act == 0) ? fmaxf(x, 0.0f)
                       : (act == 1) ? 0.5f * (th + 1.0f)
                                    : th;
        so[bq * 16 + k][ol] = y;
    }
    __syncthreads();

    if (*s_ok) {
        // Coalesced tile write: 4 rows x 256 B contiguous per wave-instr,
        // full-line NT stores.
        const int c4 = tid & 15;
        const int rb = tid >> 4;       // 0..15
        const int o0 = bid * 64;
        #pragma unroll
        for (int p = 0; p < 4; ++p) {
            const int r = rb + p * 16;
            f4v v;
            v.x = so[r][c4 * 4 + 0];
            v.y = so[r][c4 * 4 + 1];
            v.z = so[r][c4 * 4 + 2];
            v.w = so[r][c4 * 4 + 3];
            __builtin_nontemporal_store(
                v, (f4v*)(out + (size_t)r * TAPE_N + o0 + c4 * 4));
        }
    } else {
        // Fallback: honest scatter via output_indices.
        #pragma unroll
        for (int k = 0; k < 16; ++k)
            __builtin_nontemporal_store(
                so[bq * 16 + k][ol],
                out + (size_t)(bq * 16 + k) * TAPE_N + od);
    }
}

// ===========================================================================
// Kernel 2 (round-10): ORDER-STAGGERED temporal fuse.
// Round-5 post-mortem: copy-then-gather for ALL blocks ran exactly serial
// (42 us = 16.5 + 25.5) because every wave is in the same phase at the same
// time. Fix: half the blocks run gather->copy, half copy->gather, selected
// by (bid>>3)&1 so both orders are present on every XCD. At any instant
// ~half the CUs stream HBM while half sit in gather-latency shadow.
// Both paths are the same two functions -> same regalloc (VGPR~80, which
// round-5 proved runs the gather at full speed).
// ===========================================================================
__global__ __launch_bounds__(256) void neuron_copy_kernel(
    const float* __restrict__ tape,
    const _Float16* __restrict__ tape_T,
    const float* __restrict__ weights,
    const float* __restrict__ bias,
    const int*   __restrict__ input_indices,
    const int*   __restrict__ output_indices,
    const int*   __restrict__ act_ids,
    float* __restrict__ out)
{
    __shared__ float so[64][65];       // [b][o_local], +1 pad
    __shared__ int   s_ok;

    const int bid = blockIdx.x;        // 0..1023
    const int tid = threadIdx.x;

    if ((bid >> 3) & 1) {
        gather_phase(tape_T, weights, bias, input_indices, output_indices,
                     act_ids, out, so, &s_ok, bid, tid);
        copy_phase(tape, out, bid, tid);
    } else {
        copy_phase(tape, out, bid, tid);
        gather_phase(tape_T, weights, bias, input_indices, output_indices,
                     act_ids, out, so, &s_ok, bid, tid);
    }
}

// ===========================================================================
// Fallback path (ws too small): XCD-phased scalar gather on fp32 tape.
// ===========================================================================
__global__ __launch_bounds__(256) void copy_tape_kernel(
    const float4* __restrict__ src, float4* __restrict__ dst, int n4)
{
    int i = blockIdx.x * blockDim.x + threadIdx.x;
    const int stride = gridDim.x * blockDim.x;
    for (; i < n4; i += stride) dst[i] = src[i];
}

__global__ __launch_bounds__(256) void neuron_kernel(
    const float* __restrict__ tape,
    const float* __restrict__ weights,
    const float* __restrict__ bias,
    const int*   __restrict__ input_indices,
    const int*   __restrict__ output_indices,
    const int*   __restrict__ act_ids,
    float* __restrict__ out)
{
    const int grp = blockIdx.x & (XCDS - 1);
    const int j   = blockIdx.x >> 3;
    const int o   = j * 256 + threadIdx.x;

    const int4*   ip = (const int4*)(input_indices + (size_t)o * FANIN);
    const float4* wp = (const float4*)(weights      + (size_t)o * FANIN);
    const int4   i0 = ip[0], i1 = ip[1], i2 = ip[2], i3 = ip[3];
    const float4 w0 = wp[0], w1 = wp[1], w2 = wp[2], w3 = wp[3];
    const float bs  = bias[o];
    const int   act = act_ids[o];
    const int   od  = output_indices[o];

    const int b0 = grp * 8;
    #pragma unroll 1
    for (int r = 0; r < 8; ++r) {
        const int b = b0 + r;
        const float* __restrict__ t = tape + (size_t)b * TAPE_N;
        float g0  = t[i0.x], g1  = t[i0.y], g2  = t[i0.z], g3  = t[i0.w];
        float g4  = t[i1.x], g5  = t[i1.y], g6  = t[i1.z], g7  = t[i1.w];
        float g8  = t[i2.x], g9  = t[i2.y], g10 = t[i2.z], g11 = t[i2.w];
        float g12 = t[i3.x], g13 = t[i3.y], g14 = t[i3.z], g15 = t[i3.w];

        float acc = bs;
        acc += g0*w0.x;  acc += g1*w0.y;  acc += g2*w0.z;  acc += g3*w0.w;
        acc += g4*w1.x;  acc += g5*w1.y;  acc += g6*w1.z;  acc += g7*w1.w;
        acc += g8*w2.x;  acc += g9*w2.y;  acc += g10*w2.z; acc += g11*w2.w;
        acc += g12*w3.x; acc += g13*w3.y; acc += g14*w3.z; acc += g15*w3.w;

        const float x = acc;
        float z = (act == 1) ? 0.5f * x : x;
        z = fminf(fmaxf(z, -15.0f), 15.0f);
        const float e  = __expf(-2.0f * z);
        const float th = (1.0f - e) / (1.0f + e);
        const float y = (act == 0) ? fmaxf(x, 0.0f)
                       : (act == 1) ? 0.5f * (th + 1.0f)
                                    : th;

        out[(size_t)b * TAPE_N + od] = y;
    }
}

extern "C" void kernel_launch(void* const* d_in, const int* in_sizes, int n_in,
                              void* d_out, int out_size, void* d_ws, size_t ws_size,
                              hipStream_t stream)
{
    const float* tape           = (const float*)d_in[0];
    const float* weights        = (const float*)d_in[1];
    const float* bias           = (const float*)d_in[2];
    const int*   input_indices  = (const int*)d_in[3];
    const int*   output_indices = (const int*)d_in[4];
    const int*   act_ids        = (const int*)d_in[5];
    float*       out            = (float*)d_out;

    const size_t need = (size_t)TAPE_N * B_SZ * sizeof(_Float16);  // 32 MiB

    if (ws_size >= need) {
        _Float16* tape_T = (_Float16*)d_ws;
        // Kernel 1: pure fp16 transpose. 262144/64 = 4096 blocks.
        transpose_kernel<<<TAPE_N / 64, 256, 0, stream>>>(tape, tape_T);
        // Kernel 2: 1024 blocks; order-staggered copy/gather phases.
        neuron_copy_kernel<<<OUT_N / 64, 256, 0, stream>>>(
            tape, tape_T, weights, bias, input_indices, output_indices,
            act_ids, out);
    } else {
        const int n4 = (B_SZ * TAPE_N) / 4;
        copy_tape_kernel<<<4096, 256, 0, stream>>>(
            (const float4*)tape, (float4*)out, n4);
        neuron_kernel<<<XCDS * (OUT_N / 256), 256, 0, stream>>>(
            tape, weights, bias, input_indices, output_indices, act_ids, out);
    }
}

// Round 7
// 154.549 us; speedup vs baseline: 1.0529x; 1.0453x over previous
//
#include <hip/hip_runtime.h>
#include <hip/hip_fp16.h>

#define B_SZ 64
#define TAPE_N 262144
#define OUT_N 65536
#define FANIN 16
#define XCDS 8

typedef _Float16 h16v __attribute__((ext_vector_type(16)));  // 32 B
typedef _Float16 h8v  __attribute__((ext_vector_type(8)));   // 16 B
typedef float    f4v  __attribute__((ext_vector_type(4)));   // 16 B clang vec

// ===========================================================================
// Kernel 1 (round-11): fused tape->out copy + fp16 transpose, RESTRUCTURED.
// Round-0's version interleaved {NT load r -> NT store r -> LDS r} per
// iteration: each store chained 1-deep behind its load -> a DRAM read/write
// turnaround every 256 B -> 4 TB/s (38 us). Round-5's copy phase proved
// batched all-loads-then-all-stores runs at full rate. So: 4 loads, then
// 4 stores, then LDS writes. 151 MB total (saves the 50 MB tape re-read of
// the split copy kernel). Target ~25 us @ 6.1 TB/s system.
// tape_T layout: [TAPE][64] halfs (row = 128 B). Columns [0, OUT_N) skip
// the out-copy (overwritten by kernel 2's epilogue).
// LDS conflict audit: both phases exactly 2-way (free on CDNA4, m136).
// ===========================================================================
__global__ __launch_bounds__(256) void copy_transpose_kernel(
    const float* __restrict__ tape, float* __restrict__ out,
    _Float16* __restrict__ tape_T)
{
    __shared__ float lds[64][65];      // [t_local][b]
    const int t0  = blockIdx.x * 64;
    const int tid = threadIdx.x;
    const bool do_copy = (t0 >= OUT_N);

    const int t4 = tid & 15;           // which float4 within the 64-col chunk
    const int b0 = tid >> 4;           // 0..15

    // 1) all loads (4-deep in flight, one DRAM read burst)
    f4v v[4];
    #pragma unroll
    for (int r = 0; r < 4; ++r) {
        const int b = b0 + r * 16;     // 0..63
        v[r] = __builtin_nontemporal_load(
            (const f4v*)(tape + (size_t)b * TAPE_N + t0 + t4 * 4));
    }
    // 2) all copy stores (one DRAM write burst, single turnaround)
    if (do_copy) {
        #pragma unroll
        for (int r = 0; r < 4; ++r) {
            const int b = b0 + r * 16;
            __builtin_nontemporal_store(
                v[r], (f4v*)(out + (size_t)b * TAPE_N + t0 + t4 * 4));
        }
    }
    // 3) LDS stage
    #pragma unroll
    for (int r = 0; r < 4; ++r) {
        const int b = b0 + r * 16;
        lds[t4 * 4 + 0][b] = v[r].x;
        lds[t4 * 4 + 1][b] = v[r].y;
        lds[t4 * 4 + 2][b] = v[r].z;
        lds[t4 * 4 + 3][b] = v[r].w;
    }
    __syncthreads();

    // Write phase: row t of tape_T = 64 halfs = 128 B = 8 chunks of 16 B.
    // Per wave: rows t0+0..31, full 128 B each -> 4 KB contiguous.
    const int c    = tid & 7;          // 16 B chunk within row
    const int trow = tid >> 3;         // 0..31
    #pragma unroll
    for (int p = 0; p < 2; ++p) {
        const int t = trow + p * 32;
        h8v v2;
        #pragma unroll
        for (int j = 0; j < 8; ++j) v2[j] = (_Float16)lds[t][c * 8 + j];
        *(h8v*)(tape_T + (size_t)(t0 + t) * 64 + c * 8) = v2;  // cached store
    }
}

// ===========================================================================
// Kernel 2: PURE gather (round-3 proven, 25.5 us measured in R5's serial
// breakdown; system-BW-bound at 6.1 TB/s -> nothing to overlap, R5/R6).
// Quartet-major lanes (o = bid*64 + tid>>2, bq = tid&3 -> each gather
// instr = 16 coalesced 128 B lines, line fully consumed), FULL 16-deep
// static unroll (rule #20: compile-time idx -> registers), LDS-tiled
// coalesced epilogue (removes the 3x partial-line write amplification).
// ===========================================================================
__global__ __launch_bounds__(256) void neuron_t_kernel(
    const _Float16* __restrict__ tape_T,
    const float* __restrict__ weights,
    const float* __restrict__ bias,
    const int*   __restrict__ input_indices,
    const int*   __restrict__ output_indices,
    const int*   __restrict__ act_ids,
    float* __restrict__ out)
{
    __shared__ float so[64][65];       // [b][o_local], +1 pad
    __shared__ int   s_ok;

    const int tid = threadIdx.x;
    const int ol  = tid >> 2;                       // 0..63, output within blk
    const int o   = blockIdx.x * 64 + ol;
    const int bq  = tid & 3;                        // quartet lane: b = bq*16+k

    if (tid == 0) s_ok = 1;

    const int4*   ip = (const int4*)(input_indices + (size_t)o * FANIN);
    const float4* wp = (const float4*)(weights      + (size_t)o * FANIN);
    const int4   I0 = ip[0], I1 = ip[1], I2 = ip[2], I3 = ip[3];
    const float4 W0 = wp[0], W1 = wp[1], W2 = wp[2], W3 = wp[3];
    const float bs  = bias[o];
    const int   act = act_ids[o];
    const int   od  = output_indices[o];

    const int   idx[16] = {I0.x, I0.y, I0.z, I0.w, I1.x, I1.y, I1.z, I1.w,
                           I2.x, I2.y, I2.z, I2.w, I3.x, I3.y, I3.z, I3.w};
    const float wv[16]  = {W0.x, W0.y, W0.z, W0.w, W1.x, W1.y, W1.z, W1.w,
                           W2.x, W2.y, W2.z, W2.w, W3.x, W3.y, W3.z, W3.w};

    float acc[16];
    #pragma unroll
    for (int k = 0; k < 16; ++k) acc[k] = bs;

    const _Float16* tb = tape_T + bq * 16;          // this quarter's 32 B slot

    #pragma unroll
    for (int f = 0; f < FANIN; ++f) {               // FULL unroll: static idx
        const h16v v = *(const h16v*)(tb + (size_t)idx[f] * 64);
        const float w = wv[f];
        #pragma unroll
        for (int k = 0; k < 16; ++k) acc[k] += w * (float)v[k];
    }

    if (od != o) s_ok = 0;   // benign race: only 0 is ever written

    // Activation -> LDS tile.
    #pragma unroll
    for (int k = 0; k < 16; ++k) {
        const float x = acc[k];
        float z = (act == 1) ? 0.5f * x : x;
        z = fminf(fmaxf(z, -15.0f), 15.0f);
        const float e  = __expf(-2.0f * z);
        const float th = (1.0f - e) / (1.0f + e);   // tanh(z)
        const float y = (act == 0) ? fmaxf(x, 0.0f)
                       : (act == 1) ? 0.5f * (th + 1.0f)
                                    : th;
        so[bq * 16 + k][ol] = y;
    }
    __syncthreads();

    if (s_ok) {
        // Coalesced tile write: 4 rows x 256 B contiguous per wave-instr,
        // full-line NT stores (no partial-line churn).
        const int c4 = tid & 15;
        const int rb = tid >> 4;       // 0..15
        const int o0 = blockIdx.x * 64;
        #pragma unroll
        for (int p = 0; p < 4; ++p) {
            const int r = rb + p * 16;
            f4v v;
            v.x = so[r][c4 * 4 + 0];
            v.y = so[r][c4 * 4 + 1];
            v.z = so[r][c4 * 4 + 2];
            v.w = so[r][c4 * 4 + 3];
            __builtin_nontemporal_store(
                v, (f4v*)(out + (size_t)r * TAPE_N + o0 + c4 * 4));
        }
    } else {
        // Fallback: honest scatter via output_indices.
        #pragma unroll
        for (int k = 0; k < 16; ++k)
            __builtin_nontemporal_store(
                so[bq * 16 + k][ol],
                out + (size_t)(bq * 16 + k) * TAPE_N + od);
    }
}

// ===========================================================================
// Fallback path (ws too small): XCD-phased scalar gather on fp32 tape.
// ===========================================================================
__global__ __launch_bounds__(256) void copy_tape_kernel(
    const float4* __restrict__ src, float4* __restrict__ dst, int n4)
{
    int i = blockIdx.x * blockDim.x + threadIdx.x;
    const int stride = gridDim.x * blockDim.x;
    for (; i < n4; i += stride) dst[i] = src[i];
}

__global__ __launch_bounds__(256) void neuron_kernel(
    const float* __restrict__ tape,
    const float* __restrict__ weights,
    const float* __restrict__ bias,
    const int*   __restrict__ input_indices,
    const int*   __restrict__ output_indices,
    const int*   __restrict__ act_ids,
    float* __restrict__ out)
{
    const int grp = blockIdx.x & (XCDS - 1);
    const int j   = blockIdx.x >> 3;
    const int o   = j * 256 + threadIdx.x;

    const int4*   ip = (const int4*)(input_indices + (size_t)o * FANIN);
    const float4* wp = (const float4*)(weights      + (size_t)o * FANIN);
    const int4   i0 = ip[0], i1 = ip[1], i2 = ip[2], i3 = ip[3];
    const float4 w0 = wp[0], w1 = wp[1], w2 = wp[2], w3 = wp[3];
    const float bs  = bias[o];
    const int   act = act_ids[o];
    const int   od  = output_indices[o];

    const int b0 = grp * 8;
    #pragma unroll 1
    for (int r = 0; r < 8; ++r) {
        const int b = b0 + r;
        const float* __restrict__ t = tape + (size_t)b * TAPE_N;
        float g0  = t[i0.x], g1  = t[i0.y], g2  = t[i0.z], g3  = t[i0.w];
        float g4  = t[i1.x], g5  = t[i1.y], g6  = t[i1.z], g7  = t[i1.w];
        float g8  = t[i2.x], g9  = t[i2.y], g10 = t[i2.z], g11 = t[i2.w];
        float g12 = t[i3.x], g13 = t[i3.y], g14 = t[i3.z], g15 = t[i3.w];

        float acc = bs;
        acc += g0*w0.x;  acc += g1*w0.y;  acc += g2*w0.z;  acc += g3*w0.w;
        acc += g4*w1.x;  acc += g5*w1.y;  acc += g6*w1.z;  acc += g7*w1.w;
        acc += g8*w2.x;  acc += g9*w2.y;  acc += g10*w2.z; acc += g11*w2.w;
        acc += g12*w3.x; acc += g13*w3.y; acc += g14*w3.z; acc += g15*w3.w;

        const float x = acc;
        float z = (act == 1) ? 0.5f * x : x;
        z = fminf(fmaxf(z, -15.0f), 15.0f);
        const float e  = __expf(-2.0f * z);
        const float th = (1.0f - e) / (1.0f + e);
        const float y = (act == 0) ? fmaxf(x, 0.0f)
                       : (act == 1) ? 0.5f * (th + 1.0f)
                                    : th;

        out[(size_t)b * TAPE_N + od] = y;
    }
}

extern "C" void kernel_launch(void* const* d_in, const int* in_sizes, int n_in,
                              void* d_out, int out_size, void* d_ws, size_t ws_size,
                              hipStream_t stream)
{
    const float* tape           = (const float*)d_in[0];
    const float* weights        = (const float*)d_in[1];
    const float* bias           = (const float*)d_in[2];
    const int*   input_indices  = (const int*)d_in[3];
    const int*   output_indices = (const int*)d_in[4];
    const int*   act_ids        = (const int*)d_in[5];
    float*       out            = (float*)d_out;

    const size_t need = (size_t)TAPE_N * B_SZ * sizeof(_Float16);  // 32 MiB

    if (ws_size >= need) {
        _Float16* tape_T = (_Float16*)d_ws;
        // Kernel 1: fused copy+transpose (batched streams). 4096 blocks.
        copy_transpose_kernel<<<TAPE_N / 64, 256, 0, stream>>>(tape, out, tape_T);
        // Kernel 2: pure gather. 1024 blocks.
        neuron_t_kernel<<<OUT_N / 64, 256, 0, stream>>>(
            tape_T, weights, bias, input_indices, output_indices, act_ids, out);
    } else {
        const int n4 = (B_SZ * TAPE_N) / 4;
        copy_tape_kernel<<<4096, 256, 0, stream>>>(
            (const float4*)tape, (float4*)out, n4);
        neuron_kernel<<<XCDS * (OUT_N / 256), 256, 0, stream>>>(
            tape, weights, bias, input_indices, output_indices, act_ids, out);
    }
}